// Round 5
// baseline (17087.717 us; speedup 1.0000x reference)
//
#include <hip/hip_runtime.h>
#include <math.h>

#define TT 512
#define BB 128
#define HH 1024
#define VV 256
#define NTHR 512
#define NBLK 256

typedef __attribute__((ext_vector_type(4))) int   i32x4;
typedef __attribute__((ext_vector_type(8))) short s16x8;
typedef __attribute__((ext_vector_type(4))) float f32x4;

__device__ __forceinline__ float sigf(float x){ return 1.0f/(1.0f+expf(-x)); }
__device__ __forceinline__ unsigned short bf16hi(float f){
  unsigned u = __float_as_uint(f);
  unsigned r = u + 0x7FFFu + ((u>>16)&1u);
  return (unsigned short)(r>>16);
}
__device__ __forceinline__ float bf16dec(unsigned short h){ return __uint_as_float(((unsigned)h)<<16); }
__device__ __forceinline__ void st16(unsigned short* p, unsigned short v){
  __hip_atomic_store(p, v, __ATOMIC_RELAXED, __HIP_MEMORY_SCOPE_AGENT);
}
__device__ __forceinline__ void st_dev(float* p, float v){
  __hip_atomic_store(p, v, __ATOMIC_RELAXED, __HIP_MEMORY_SCOPE_AGENT);
}

// Grid barrier (contention-free) + per-step XCD-L2/L1 invalidate.
// All global WRITES in this kernel are agent-scope write-through (sc1), so the
// acquire fence (buffer_inv, no writeback) never discards dirty data. After the
// fence, plain cached loads see fresh data AND share lines in the XCD's L2.
__device__ __forceinline__ void gbar(unsigned* flags, unsigned rnd, int tid, int bid){
  __syncthreads();   // drains vmcnt: this block's sc1 stores are device-visible
  if (tid == 0) __hip_atomic_store(&flags[bid], rnd, __ATOMIC_RELAXED, __HIP_MEMORY_SCOPE_AGENT);
  if (tid < NBLK) {
    int spins = 0;
    while (__hip_atomic_load(&flags[tid], __ATOMIC_RELAXED, __HIP_MEMORY_SCOPE_AGENT) < rnd) {
      __builtin_amdgcn_s_sleep(1);
      if (++spins > (1<<28)) break;   // deadlock insurance
    }
  }
  __syncthreads();                    // everyone knows: all blocks arrived
  if (tid == 0) __builtin_amdgcn_fence(__ATOMIC_ACQUIRE, "agent");  // inv L1+L2 (once per CU)
  __syncthreads();                    // no load issues before the inv completed
}

// one 3-pass (hi/lo x hi/lo, lo*lo dropped) K=32 MFMA step against staged w-frags
#define GBODY(AH, AL, KC) { \
  s16x8 bh_ = *(const s16x8*)&wlds[(((KC)*2+0)*64+lane)*8]; \
  s16x8 bl_ = *(const s16x8*)&wlds[(((KC)*2+1)*64+lane)*8]; \
  s16x8 ah_ = __builtin_bit_cast(s16x8, AH); \
  s16x8 al_ = __builtin_bit_cast(s16x8, AL); \
  acc = __builtin_amdgcn_mfma_f32_16x16x32_bf16(ah_, bh_, acc, 0,0,0); \
  acc = __builtin_amdgcn_mfma_f32_16x16x32_bf16(ah_, bl_, acc, 0,0,0); \
  acc = __builtin_amdgcn_mfma_f32_16x16x32_bf16(al_, bh_, acc, 0,0,0); \
}

// hF layout: [strip s 0..7][kc 0..31][plane hi/lo][lane 0..63][j 0..7] bf16
// A-frag for (s,kc,plane) = one coalesced 16B/lane load at lane*16.
// element (b,k): s=b>>4, kc=k>>5, lane=(b&15)+16*((k>>3)&3), j=k&7.

__global__ __launch_bounds__(NTHR, 1)
void lstm_mfma(
    const int*   __restrict__ x,
    const float* __restrict__ Wgx, const float* __restrict__ Wgh,
    const float* __restrict__ Wix, const float* __restrict__ Wih,
    const float* __restrict__ Wfx, const float* __restrict__ Wfh,
    const float* __restrict__ Wox, const float* __restrict__ Woh,
    const float* __restrict__ Wph,
    const float* __restrict__ bg,  const float* __restrict__ bi,
    const float* __restrict__ bf_, const float* __restrict__ bo,
    const float* __restrict__ bp,
    float* __restrict__ seq, char* __restrict__ hFA, char* __restrict__ hFB,
    float* __restrict__ gpart, int* __restrict__ xT, unsigned* __restrict__ flags)
{
  __shared__ unsigned short wlds[40*2*64*8];   // gate B-frags hi/lo   80 KB
  __shared__ unsigned short wplds[16*2*64*8];  // wph B-frags          32 KB
  __shared__ float zex[BB*17];                 // gate D exchange (pad17)  8.5 KB
  __shared__ float pex[8*256];                 // p D partials          8 KB
  __shared__ float wxl[VV*17];                 // L0 x-gather table (pad17) 17.4 KB

  const int tid = threadIdx.x, bid = blockIdx.x;
  const int wv   = tid>>6;        // wave id = gate row-strip
  const int lane = tid&63;
  const int jb   = bid*4;         // hcol base (block owns 16 cols = 4 gates x 4 hcols)
  const int p_cg = bid & 15;      // p-slice: col-group (pcols p_cg*16..+15)
  const int p_s  = (bid>>4)&7;    //          row strip
  const int p_kh = bid>>7;        //          k-half (0/1)
  const int u_hc = tid>>7, u_b = tid&127;   // update mapping: (hcol, row)

  unsigned roundNo = 0;

  // stage xT[t][b] once (sc1 so later cached reads are fresh after inv)
  for (int i = bid*NTHR+tid; i < BB*TT; i += NBLK*NTHR) {
    int b = i>>9, t = i&(TT-1);
    __hip_atomic_store(&xT[t*BB+b], x[i], __ATOMIC_RELAXED, __HIP_MEMORY_SCOPE_AGENT);
  }

  for (int layer = 0; layer < 2; ++layer) {
    const float* Wgh_l = Wgh + (size_t)layer*HH*HH;
    const float* Wih_l = Wih + (size_t)layer*HH*HH;
    const float* Wfh_l = Wfh + (size_t)layer*HH*HH;
    const float* Woh_l = Woh + (size_t)layer*HH*HH;
    const float* Wgx_l = Wgx + (size_t)layer*VV*HH;
    const float* Wix_l = Wix + (size_t)layer*VV*HH;
    const float* Wfx_l = Wfx + (size_t)layer*VV*HH;
    const float* Wox_l = Wox + (size_t)layer*VV*HH;
    const float* Wph_l = Wph + (size_t)layer*HH*VV;
    const float* bg_l = bg + layer*HH, *bi_l = bi + layer*HH;
    const float* bf_l = bf_ + layer*HH, *bo_l = bo + layer*HH;
    const float* bp_l = bp + layer*VV;
    const int KCTOT = layer ? 40 : 32;   // kc count incl. L1's p0 K-extension

    // ---- stage gate-weight B-frags (hi/lo), once per layer ----
    for (int idx = tid; idx < KCTOT*64; idx += NTHR) {
      int kc = idx>>6, ln = idx&63;
      int col = ln&15, koct = ln>>4;
      int g = col>>2, hcl = col&3;
      const float* Wh = (g==0)?Wgh_l:(g==1)?Wih_l:(g==2)?Wfh_l:Woh_l;
      const float* Wx = (g==0)?Wgx_l:(g==1)?Wix_l:(g==2)?Wfx_l:Wox_l;
      #pragma unroll
      for (int j = 0; j < 8; ++j) {
        int k = kc*32 + koct*8 + j;
        float w = (k < HH) ? Wh[(size_t)k*HH + jb + hcl]
                           : Wx[(size_t)(k-HH)*HH + jb + hcl];
        unsigned short hi = bf16hi(w);
        wlds[((kc*2+0)*64+ln)*8+j] = hi;
        wlds[((kc*2+1)*64+ln)*8+j] = bf16hi(w - bf16dec(hi));
      }
    }
    // ---- stage wph B-frags for this block's p-slice ----
    for (int idx = tid; idx < 16*64; idx += NTHR) {
      int pbq = idx>>6, ln = idx&63;
      int pcol = p_cg*16 + (ln&15);
      #pragma unroll
      for (int j = 0; j < 8; ++j) {
        int k = p_kh*512 + pbq*32 + (ln>>4)*8 + j;
        float w = Wph_l[(size_t)k*VV + pcol];
        unsigned short hi = bf16hi(w);
        wplds[((pbq*2+0)*64+ln)*8+j] = hi;
        wplds[((pbq*2+1)*64+ln)*8+j] = bf16hi(w - bf16dec(hi));
      }
    }
    // ---- stage L0 x-gather table: wxl[tok][g*4+hc], pad-17 ----
    if (layer == 0) {
      for (int idx = tid; idx < VV*16; idx += NTHR) {
        int v = idx>>4, c = idx&15;
        int g = c>>2, hcl = c&3;
        const float* Wx = (g==0)?Wgx_l:(g==1)?Wix_l:(g==2)?Wfx_l:Wox_l;
        wxl[v*17 + c] = Wx[(size_t)v*HH + jb + hcl];
      }
    }
    float c_reg = 0.f, own_prev = 0.f;
    gbar(flags, ++roundNo, tid, bid);

    for (int t = 0; t <= TT+1; ++t) {
      const char* hprev = (t&1) ? hFA : hFB;   // h[t-1]
      char*       hcur  = (t&1) ? hFB : hFA;   // h[t]
      const bool gates_on = (t < TT);
      const bool p_on     = (t >= 1 && t <= TT);
      const bool hrun     = gates_on && (t > 0);
      const bool ranz     = gates_on && (t > 0 || layer == 1);

      // ---- finalize p[t-2]: own(prev step) + partner partial + bias ----
      if (t >= 2 && p_kh == 0 && tid < 256) {
        float partner = gpart[(size_t)((t-1)&1)*NBLK*256 + (size_t)(bid+128)*256 + tid];
        int row = tid>>4, col = tid&15;
        int pcol = p_cg*16 + col;
        float pv = own_prev + partner + bp_l[pcol];
        if (layer == 0) {  // p0 -> frag-packed bf16 hi/lo into d_out slice t-2
          unsigned short hi = bf16hi(pv);
          unsigned short lo = bf16hi(pv - bf16dec(hi));
          size_t off = (size_t)(t-2)*131072 + (size_t)p_s*16384 + (size_t)(pcol>>5)*2048
                     + (size_t)(row + 16*((pcol>>3)&3))*16 + (size_t)(pcol&7)*2;
          unsigned short* o = (unsigned short*)((char*)seq + off);
          st16(o, hi); st16(o + 512, lo);        // +512 shorts = lo plane (+1024 B)
        } else {           // p1 -> final fp32 output (sc1: keep L2 clean for inv)
          int b = p_s*16 + row;
          st_dev(&seq[(size_t)(t-2)*BB*VV + (size_t)b*VV + pcol], pv);
        }
      }

      // ---- gate GEMM: h-part (kc 0..31), plain cached loads (L2-shared) ----
      f32x4 acc = {0.f,0.f,0.f,0.f};
      if (hrun) {
        const char* ab = hprev + (size_t)wv*65536 + (size_t)lane*16;  // strip stride 32*2*1024
        for (int kc = 0; kc < 32; kc += 4) {
          const char* a0 = ab + (size_t)kc*2048;
          i32x4 q0 = *(const i32x4*)(a0);
          i32x4 q1 = *(const i32x4*)(a0+1024);
          i32x4 q2 = *(const i32x4*)(a0+2048);
          i32x4 q3 = *(const i32x4*)(a0+3072);
          i32x4 q4 = *(const i32x4*)(a0+4096);
          i32x4 q5 = *(const i32x4*)(a0+5120);
          i32x4 q6 = *(const i32x4*)(a0+6144);
          i32x4 q7 = *(const i32x4*)(a0+7168);
          GBODY(q0,q1,kc); GBODY(q2,q3,kc+1); GBODY(q4,q5,kc+2); GBODY(q6,q7,kc+3);
        }
      }
      // ---- gate GEMM: L1 K-extension from p0F (kc 32..39) ----
      if (gates_on && layer == 1) {
        const char* eb = (const char*)seq + (size_t)t*131072 + (size_t)wv*16384 + (size_t)lane*16;
        for (int kc2 = 0; kc2 < 8; kc2 += 4) {
          const char* a0 = eb + (size_t)kc2*2048;
          i32x4 q0 = *(const i32x4*)(a0);
          i32x4 q1 = *(const i32x4*)(a0+1024);
          i32x4 q2 = *(const i32x4*)(a0+2048);
          i32x4 q3 = *(const i32x4*)(a0+3072);
          i32x4 q4 = *(const i32x4*)(a0+4096);
          i32x4 q5 = *(const i32x4*)(a0+5120);
          i32x4 q6 = *(const i32x4*)(a0+6144);
          i32x4 q7 = *(const i32x4*)(a0+7168);
          GBODY(q0,q1,32+kc2); GBODY(q2,q3,33+kc2); GBODY(q4,q5,34+kc2); GBODY(q6,q7,35+kc2);
        }
      }

      // ---- p-slice partial (2 kc per wave, from h[t-1] at strip p_s) ----
      f32x4 pacc = {0.f,0.f,0.f,0.f};
      if (p_on) {
        const int kcp = p_kh*16 + wv*2;
        const int pbq = wv*2;
        const char* pb_ = hprev + (size_t)p_s*65536 + (size_t)kcp*2048 + (size_t)lane*16;
        s16x8 b0h = *(const s16x8*)&wplds[((pbq*2+0)*64+lane)*8];
        s16x8 b0l = *(const s16x8*)&wplds[((pbq*2+1)*64+lane)*8];
        s16x8 b1h = *(const s16x8*)&wplds[(((pbq+1)*2+0)*64+lane)*8];
        s16x8 b1l = *(const s16x8*)&wplds[(((pbq+1)*2+1)*64+lane)*8];
        i32x4 a0 = *(const i32x4*)(pb_);
        i32x4 a1 = *(const i32x4*)(pb_+1024);
        i32x4 a2 = *(const i32x4*)(pb_+2048);
        i32x4 a3 = *(const i32x4*)(pb_+3072);
        s16x8 A0h = __builtin_bit_cast(s16x8, a0), A0l = __builtin_bit_cast(s16x8, a1);
        s16x8 A1h = __builtin_bit_cast(s16x8, a2), A1l = __builtin_bit_cast(s16x8, a3);
        pacc = __builtin_amdgcn_mfma_f32_16x16x32_bf16(A0h, b0h, pacc, 0,0,0);
        pacc = __builtin_amdgcn_mfma_f32_16x16x32_bf16(A0h, b0l, pacc, 0,0,0);
        pacc = __builtin_amdgcn_mfma_f32_16x16x32_bf16(A0l, b0h, pacc, 0,0,0);
        pacc = __builtin_amdgcn_mfma_f32_16x16x32_bf16(A1h, b1h, pacc, 0,0,0);
        pacc = __builtin_amdgcn_mfma_f32_16x16x32_bf16(A1h, b1l, pacc, 0,0,0);
        pacc = __builtin_amdgcn_mfma_f32_16x16x32_bf16(A1l, b1h, pacc, 0,0,0);
      }

      // ---- D-frag exchange (col = lane&15, row = (lane>>4)*4 + reg) ----
      if (ranz) {
        int q = lane>>4, c0 = lane&15;
        zex[(wv*16 + q*4 + 0)*17 + c0] = acc.x;
        zex[(wv*16 + q*4 + 1)*17 + c0] = acc.y;
        zex[(wv*16 + q*4 + 2)*17 + c0] = acc.z;
        zex[(wv*16 + q*4 + 3)*17 + c0] = acc.w;
      }
      if (p_on) {
        int q = lane>>4, c0 = lane&15;
        pex[wv*256 + (q*4 + 0)*16 + c0] = pacc.x;
        pex[wv*256 + (q*4 + 1)*16 + c0] = pacc.y;
        pex[wv*256 + (q*4 + 2)*16 + c0] = pacc.z;
        pex[wv*256 + (q*4 + 3)*16 + c0] = pacc.w;
      }
      __syncthreads();

      // ---- LSTM cell update ----
      if (gates_on) {
        float z0 = bg_l[jb+u_hc], z1 = bi_l[jb+u_hc], z2 = bf_l[jb+u_hc], z3 = bo_l[jb+u_hc];
        if (ranz) {
          z0 += zex[u_b*17 +  0 + u_hc];
          z1 += zex[u_b*17 +  4 + u_hc];
          z2 += zex[u_b*17 +  8 + u_hc];
          z3 += zex[u_b*17 + 12 + u_hc];
        }
        if (layer == 0) {   // one-hot x contribution from LDS table
          int tok = xT[t*BB + u_b];
          z0 += wxl[tok*17 +  0 + u_hc];
          z1 += wxl[tok*17 +  4 + u_hc];
          z2 += wxl[tok*17 +  8 + u_hc];
          z3 += wxl[tok*17 + 12 + u_hc];
        }
        float G = tanhf(z0), I = sigf(z1), F = sigf(z2), O = sigf(z3);
        c_reg = fmaf(G, I, c_reg * F);
        float hv = tanhf(c_reg) * O;
        int k = jb + u_hc;
        size_t off = ((size_t)(u_b>>4)*32 + (size_t)(k>>5))*2048
                   + (size_t)((u_b&15) + 16*((k>>3)&3))*16 + (size_t)(k&7)*2;
        unsigned short* o = (unsigned short*)(hcur + off);
        unsigned short hh = bf16hi(hv);
        st16(o, hh); st16(o + 512, bf16hi(hv - bf16dec(hh)));
      }
      // ---- p partial block-sum + publish ----
      if (p_on && tid < 256) {
        float s = 0.f;
        #pragma unroll
        for (int wq = 0; wq < 8; ++wq) s += pex[wq*256 + tid];
        __hip_atomic_store(&gpart[(size_t)(t&1)*NBLK*256 + (size_t)bid*256 + tid], s,
                           __ATOMIC_RELAXED, __HIP_MEMORY_SCOPE_AGENT);
        own_prev = s;
      }
      gbar(flags, ++roundNo, tid, bid);
    }
  }
}

extern "C" void kernel_launch(void* const* d_in, const int* in_sizes, int n_in,
                              void* d_out, int out_size, void* d_ws, size_t ws_size,
                              hipStream_t stream)
{
  const int*   x   = (const int*)  d_in[0];
  const float* Wgx = (const float*)d_in[1];
  const float* Wgh = (const float*)d_in[2];
  const float* Wix = (const float*)d_in[3];
  const float* Wih = (const float*)d_in[4];
  const float* Wfx = (const float*)d_in[5];
  const float* Wfh = (const float*)d_in[6];
  const float* Wox = (const float*)d_in[7];
  const float* Woh = (const float*)d_in[8];
  const float* Wph = (const float*)d_in[9];
  const float* bg  = (const float*)d_in[10];
  const float* bi  = (const float*)d_in[11];
  const float* bf  = (const float*)d_in[12];
  const float* bo  = (const float*)d_in[13];
  const float* bp  = (const float*)d_in[14];

  float*    seq   = (float*)d_out;
  char*     base  = (char*)d_ws;
  unsigned* flags = (unsigned*)base;                 //   4 KB
  int*      xT    = (int*)(base + 4096);             // 256 KB
  char*     hFA   = base + 4096 + 262144;            // 512 KB
  char*     hFB   = hFA + 524288;                    // 512 KB
  float*    gpart = (float*)(hFB + 524288);          // 512 KB

  hipMemsetAsync(flags, 0, 4096, stream);

  void* args[] = { (void*)&x,
                   (void*)&Wgx, (void*)&Wgh, (void*)&Wix, (void*)&Wih,
                   (void*)&Wfx, (void*)&Wfh, (void*)&Wox, (void*)&Woh,
                   (void*)&Wph,
                   (void*)&bg, (void*)&bi, (void*)&bf, (void*)&bo, (void*)&bp,
                   (void*)&seq, (void*)&hFA, (void*)&hFB,
                   (void*)&gpart, (void*)&xT, (void*)&flags };

  hipLaunchCooperativeKernel((const void*)lstm_mfma, dim3(NBLK), dim3(NTHR),
                             args, 0, stream);
}

// Round 6
// 10227.290 us; speedup vs baseline: 1.6708x; 1.6708x over previous
//
#include <hip/hip_runtime.h>
#include <math.h>

#define TT 512
#define BB 128
#define HH 1024
#define VV 256
#define NTHR 512
#define NBLK 160
#define NGATE 128

typedef __attribute__((ext_vector_type(4)))  int      i32x4;
typedef __attribute__((ext_vector_type(8)))  _Float16 f16x8;
typedef __attribute__((ext_vector_type(16))) float    f32x16;

#define ZEX_OFF  0
#define WXL_OFF  67584
#define BIAS_OFF 101376
#define SMEM_SZ  101504

__device__ __forceinline__ float sigf(float x){ return 1.0f/(1.0f+expf(-x)); }
__device__ __forceinline__ void st16(unsigned short* p, unsigned short v){
  __hip_atomic_store(p, v, __ATOMIC_RELAXED, __HIP_MEMORY_SCOPE_AGENT);
}
__device__ __forceinline__ void stf(float* p, float v){
  __hip_atomic_store(p, v, __ATOMIC_RELAXED, __HIP_MEMORY_SCOPE_AGENT);
}
__device__ __forceinline__ unsigned short h2u(_Float16 h){
  union { _Float16 h; unsigned short u; } c; c.h = h; return c.u;
}

// device-coherent 16B load (bypasses possibly-stale per-XCD L2)
#define SCLOAD(dst, ptr) asm volatile("global_load_dwordx4 %0, %1, off sc1" : "=v"(dst) : "v"(ptr))
// counted wait tied to the 8 frags being consumed (dataflow stops MFMA hoisting)
#define WAITG(Q, N) asm volatile("s_waitcnt vmcnt(" #N ")" \
  : "+v"(Q[0]),"+v"(Q[1]),"+v"(Q[2]),"+v"(Q[3]),"+v"(Q[4]),"+v"(Q[5]),"+v"(Q[6]),"+v"(Q[7]))

// contention-free grid barrier: per-block flags, parallel poll, NO cache fences
__device__ __forceinline__ void gbar(unsigned* flags, unsigned rnd, int tid, int bid){
  __syncthreads();   // drains vmcnt: this block's sc1 stores are device-visible
  if (tid == 0) __hip_atomic_store(&flags[bid], rnd, __ATOMIC_RELAXED, __HIP_MEMORY_SCOPE_AGENT);
  if (tid < NBLK) {
    int spins = 0;
    while (__hip_atomic_load(&flags[tid], __ATOMIC_RELAXED, __HIP_MEMORY_SCOPE_AGENT) < rnd) {
      __builtin_amdgcn_s_sleep(1);
      if (++spins > (1<<28)) break;   // deadlock insurance
    }
  }
  __syncthreads();
}

// A address: h part (m<64) or L1 K-extension from p0 frags in seq (m>=64)
#define AADDR(M, HB, EB) (((M) < 64) ? ((HB) + (size_t)(M)*1024) : ((EB) + (size_t)((M)-64)*1024))

#define ISSUE_GRP(Q, GI) do{ \
  _Pragma("unroll") \
  for (int kk_=0; kk_<4; ++kk_){ \
    const int m_ = kq*NKW + (GI)*4 + kk_; \
    SCLOAD(Q[kk_],   AADDR(m_, hb0, eb0)); \
    SCLOAD(Q[kk_+4], AADDR(m_, hb1, eb1)); \
  } }while(0)

#define MFMA_GRP(Q, GI) do{ \
  _Pragma("unroll") \
  for (int kk_=0; kk_<4; ++kk_){ \
    const f16x8 a0_ = __builtin_bit_cast(f16x8, Q[kk_]); \
    const f16x8 a1_ = __builtin_bit_cast(f16x8, Q[kk_+4]); \
    acc0 = __builtin_amdgcn_mfma_f32_32x32x16_f16(a0_, breg[(GI)*4+kk_], acc0, 0,0,0); \
    acc1 = __builtin_amdgcn_mfma_f32_32x32x16_f16(a1_, breg[(GI)*4+kk_], acc1, 0,0,0); \
  } }while(0)

// h frag layout (fp16, 256 KB): element (b,k): byte =
//   (b>>5)*65536 + (k>>4)*1024 + ((b&31) + 32*((k>>3)&1))*16 + (k&7)*2
// (matches mfma_32x32x16_f16 A-frag: row=lane&31, k = 8*(lane>>5)+j)
// K-ext frags for L1 live in seq slice t, first 64 KB:
//   (t)*131072 + (b>>5)*16384 + (v>>4)*1024 + ((b&31)+32*((v>>3)&1))*16 + (v&7)*2

template<int LAYER>
__device__ __forceinline__ void layer_pass(
    char* smem, const int* __restrict__ xT,
    const float* __restrict__ Wgx, const float* __restrict__ Wgh,
    const float* __restrict__ Wix, const float* __restrict__ Wih,
    const float* __restrict__ Wfx, const float* __restrict__ Wfh,
    const float* __restrict__ Wox, const float* __restrict__ Woh,
    const float* __restrict__ Wph,
    const float* __restrict__ bg,  const float* __restrict__ bi,
    const float* __restrict__ bf_, const float* __restrict__ bo,
    const float* __restrict__ bp,
    float* __restrict__ seq, char* __restrict__ hFA, char* __restrict__ hFB,
    unsigned* __restrict__ flags, unsigned& roundNo)
{
  const int tid = threadIdx.x, bid = blockIdx.x;
  const int wv = tid>>6, lane = tid&63;
  constexpr int NKW = LAYER ? 20 : 16;   // kc2 (K=16 slabs) per wave
  char* seqc = (char*)seq;

  const float* Wh[4] = { Wgh + (size_t)LAYER*HH*HH, Wih + (size_t)LAYER*HH*HH,
                         Wfh + (size_t)LAYER*HH*HH, Woh + (size_t)LAYER*HH*HH };
  const float* Wx[4] = { Wgx + (size_t)LAYER*VV*HH, Wix + (size_t)LAYER*VV*HH,
                         Wfx + (size_t)LAYER*VV*HH, Wox + (size_t)LAYER*VV*HH };
  const float* bb[4] = { bg + LAYER*HH, bi + LAYER*HH, bf_ + LAYER*HH, bo + LAYER*HH };
  const float* Wph_l = Wph + (size_t)LAYER*HH*VV;
  const float* bp_l  = bp + LAYER*VV;

  const bool is_gate = bid < NGATE;
  float* zex      = (float*)(smem + ZEX_OFF);    // [rg 4][kq 4][row 32][33]
  float* wxl      = (float*)(smem + WXL_OFF);    // [tok 256][33]
  float* bias_lds = (float*)(smem + BIAS_OFF);   // [32]
  float* pex      = (float*)(smem + ZEX_OFF);    // p role: [wv 8][row 32][33]

  // gate geometry: 32 cols = 4 gates x 8 hcols; waves = (rgp 0..1) x (kq 0..3)
  const int rgp = wv>>2, kq = wv&3;
  const int rg0 = rgp*2, rg1 = rgp*2+1;
  const int jb8 = bid*8;
  // p geometry: 32 blocks, tile = 32 rows x 32 pcols, full K
  const int pb = bid - NGATE, rg_p = pb>>3, cg = pb&7;

  f16x8 breg[NKW];

  if (is_gate) {
    #pragma unroll
    for (int i=0;i<NKW;++i){
      const int m = kq*NKW + i;
      const int col = lane&31, gg = col>>3, hc = col&7;
      f16x8 v;
      #pragma unroll
      for (int j=0;j<8;++j){
        const int k = m*16 + ((lane>>5)<<3) + j;
        const float w = (k < HH) ? Wh[gg][(size_t)k*HH + jb8 + hc]
                                 : Wx[gg][(size_t)(k-HH)*HH + jb8 + hc];
        v[j] = (_Float16)w;
      }
      breg[i] = v;
    }
    if (LAYER == 0){
      for (int idx = tid; idx < VV*32; idx += NTHR){
        const int vt = idx>>5, c = idx&31, gg = c>>3, hc = c&7;
        wxl[vt*33 + c] = Wx[gg][(size_t)vt*HH + jb8 + hc];
      }
    }
    if (tid < 32) bias_lds[tid] = bb[tid>>3][jb8 + (tid&7)];
  } else {
    #pragma unroll
    for (int i=0;i<8;++i){
      const int m = wv*8 + i;
      const int pcol = cg*32 + (lane&31);
      f16x8 v;
      #pragma unroll
      for (int j=0;j<8;++j){
        const int k = m*16 + ((lane>>5)<<3) + j;
        v[j] = (_Float16)Wph_l[(size_t)k*VV + pcol];
      }
      breg[i] = v;
    }
  }

  // zero both h frag buffers (t=0 runs the full GEMM against zeros)
  for (int idx = bid*NTHR + tid; idx < 131072; idx += NBLK*NTHR){
    float* p = (idx < 65536) ? ((float*)hFA + idx) : ((float*)hFB + (idx - 65536));
    stf(p, 0.f);
  }

  float cst0 = 0.f, cst1 = 0.f;
  gbar(flags, ++roundNo, tid, bid);

  for (int t = 0; t <= TT; ++t) {
    const char* hprev = (t&1) ? hFA : hFB;
    char*       hcur  = (t&1) ? hFB : hFA;

    if (is_gate) {
      const int u_row = tid & 127, u_hq = tid>>7;
      int tok = 0;
      if (t < TT) {
        f32x16 acc0 = {0,0,0,0,0,0,0,0,0,0,0,0,0,0,0,0};
        f32x16 acc1 = {0,0,0,0,0,0,0,0,0,0,0,0,0,0,0,0};
        const char* hb0 = hprev + (size_t)rg0*65536 + (size_t)lane*16;
        const char* hb1 = hprev + (size_t)rg1*65536 + (size_t)lane*16;
        const char* eb0 = seqc + (size_t)t*131072 + (size_t)rg0*16384 + (size_t)lane*16;
        const char* eb1 = seqc + (size_t)t*131072 + (size_t)rg1*16384 + (size_t)lane*16;
        i32x4 qA[8], qB[8];

        if (LAYER == 0)  // issue token load FIRST (oldest) so vmcnt counts stay exact
          asm volatile("global_load_dword %0, %1, off sc1" : "=v"(tok) : "v"(xT + t*BB + u_row));

        ISSUE_GRP(qA, 0);
        ISSUE_GRP(qB, 1);
        WAITG(qA, 8); MFMA_GRP(qA, 0); ISSUE_GRP(qA, 2);
        WAITG(qB, 8); MFMA_GRP(qB, 1); ISSUE_GRP(qB, 3);
        if constexpr (NKW == 20) {
          WAITG(qA, 8); MFMA_GRP(qA, 2); ISSUE_GRP(qA, 4);
          WAITG(qB, 8); MFMA_GRP(qB, 3);
          WAITG(qA, 0); MFMA_GRP(qA, 4);
        } else {
          WAITG(qA, 8); MFMA_GRP(qA, 2);
          WAITG(qB, 0); MFMA_GRP(qB, 3);
        }
        if (LAYER == 0) asm volatile("" : "+v"(tok));  // tok retired by vmcnt(0) above

        // D partials -> zex  (D: col=lane&31, row=(r&3)+8*(r>>2)+4*(lane>>5))
        const int col = lane&31;
        #pragma unroll
        for (int r=0;r<16;++r){
          const int row = (r&3) + 8*(r>>2) + 4*(lane>>5);
          zex[(((rg0*4 + kq)*32) + row)*33 + col] = acc0[r];
          zex[(((rg1*4 + kq)*32) + row)*33 + col] = acc1[r];
        }
      }
      __syncthreads();
      if (t < TT) {
        #pragma unroll
        for (int e=0;e<2;++e){
          const int hc = u_hq*2 + e;
          float z[4];
          #pragma unroll
          for (int g=0; g<4; ++g){
            float s = bias_lds[g*8 + hc];
            if (LAYER == 0) s += wxl[tok*33 + g*8 + hc];
            #pragma unroll
            for (int k2=0;k2<4;++k2)
              s += zex[((((u_row>>5)*4 + k2)*32) + (u_row&31))*33 + g*8 + hc];
            z[g] = s;
          }
          const float G = tanhf(z[0]), I = sigf(z[1]), F = sigf(z[2]), O = sigf(z[3]);
          float cc = e ? cst1 : cst0;
          cc = fmaf(G, I, cc*F);
          if (e) cst1 = cc; else cst0 = cc;
          const float hv = tanhf(cc)*O;
          const int hid = jb8 + hc;
          const size_t off = (size_t)(u_row>>5)*65536 + (size_t)(hid>>4)*1024
                           + (size_t)((u_row&31) + 32*((hid>>3)&1))*16 + (size_t)(hid&7)*2;
          st16((unsigned short*)(hcur + off), h2u((_Float16)hv));
        }
      }
    } else {
      // ---- p role: p[t-1] = h[t-1] @ Wph + bp, full K in one block ----
      if (t >= 1) {
        f32x16 accp = {0,0,0,0,0,0,0,0,0,0,0,0,0,0,0,0};
        const char* pb0 = hprev + (size_t)rg_p*65536 + (size_t)lane*16;
        i32x4 qA[8];
        #pragma unroll
        for (int i=0;i<8;++i) SCLOAD(qA[i], pb0 + (size_t)(wv*8 + i)*1024);
        WAITG(qA, 0);
        #pragma unroll
        for (int i=0;i<8;++i)
          accp = __builtin_amdgcn_mfma_f32_32x32x16_f16(
                   __builtin_bit_cast(f16x8, qA[i]), breg[i], accp, 0,0,0);
        const int col = lane&31;
        #pragma unroll
        for (int r=0;r<16;++r){
          const int row = (r&3) + 8*(r>>2) + 4*(lane>>5);
          pex[(wv*32 + row)*33 + col] = accp[r];
        }
      }
      __syncthreads();
      if (t >= 1) {
        #pragma unroll
        for (int e=0;e<2;++e){
          const int o = tid + e*512;
          const int row = o>>5, col = o&31;
          const int pcol = cg*32 + col;
          float s = bp_l[pcol];
          #pragma unroll
          for (int w8=0; w8<8; ++w8) s += pex[(w8*32 + row)*33 + col];
          if (LAYER == 0) {   // p0 -> fp16 frag region of seq slice t-1 (for L1 K-ext)
            const size_t off = (size_t)(t-1)*131072 + (size_t)rg_p*16384
                             + (size_t)(pcol>>4)*1024
                             + (size_t)(row + 32*((pcol>>3)&1))*16 + (size_t)(pcol&7)*2;
            st16((unsigned short*)(seqc + off), h2u((_Float16)s));
          } else {            // p1 -> final fp32 output
            const int b = rg_p*32 + row;
            stf(seq + (size_t)(t-1)*BB*VV + (size_t)b*VV + pcol, s);
          }
        }
      }
    }
    gbar(flags, ++roundNo, tid, bid);
  }
}

__global__ __launch_bounds__(NTHR, 1)
void lstm_f16(
    const int*   __restrict__ x,
    const float* __restrict__ Wgx, const float* __restrict__ Wgh,
    const float* __restrict__ Wix, const float* __restrict__ Wih,
    const float* __restrict__ Wfx, const float* __restrict__ Wfh,
    const float* __restrict__ Wox, const float* __restrict__ Woh,
    const float* __restrict__ Wph,
    const float* __restrict__ bg,  const float* __restrict__ bi,
    const float* __restrict__ bf_, const float* __restrict__ bo,
    const float* __restrict__ bp,
    float* __restrict__ seq, char* __restrict__ hFA, char* __restrict__ hFB,
    int* __restrict__ xT, unsigned* __restrict__ flags)
{
  __shared__ char smem[SMEM_SZ];
  const int tid = threadIdx.x, bid = blockIdx.x;
  unsigned roundNo = 0;

  // transpose x[B][T] -> xT[t][b] once (sc1 stores)
  for (int i = bid*NTHR + tid; i < BB*TT; i += NBLK*NTHR) {
    const int b = i >> 9, t = i & (TT-1);
    __hip_atomic_store(&xT[t*BB + b], x[i], __ATOMIC_RELAXED, __HIP_MEMORY_SCOPE_AGENT);
  }

  layer_pass<0>(smem, xT, Wgx,Wgh,Wix,Wih,Wfx,Wfh,Wox,Woh,Wph,
                bg,bi,bf_,bo,bp, seq, hFA, hFB, flags, roundNo);
  layer_pass<1>(smem, xT, Wgx,Wgh,Wix,Wih,Wfx,Wfh,Wox,Woh,Wph,
                bg,bi,bf_,bo,bp, seq, hFA, hFB, flags, roundNo);
}

extern "C" void kernel_launch(void* const* d_in, const int* in_sizes, int n_in,
                              void* d_out, int out_size, void* d_ws, size_t ws_size,
                              hipStream_t stream)
{
  const int*   x   = (const int*)  d_in[0];
  const float* Wgx = (const float*)d_in[1];
  const float* Wgh = (const float*)d_in[2];
  const float* Wix = (const float*)d_in[3];
  const float* Wih = (const float*)d_in[4];
  const float* Wfx = (const float*)d_in[5];
  const float* Wfh = (const float*)d_in[6];
  const float* Wox = (const float*)d_in[7];
  const float* Woh = (const float*)d_in[8];
  const float* Wph = (const float*)d_in[9];
  const float* bg  = (const float*)d_in[10];
  const float* bi  = (const float*)d_in[11];
  const float* bf  = (const float*)d_in[12];
  const float* bo  = (const float*)d_in[13];
  const float* bp  = (const float*)d_in[14];

  float*    seq   = (float*)d_out;
  char*     base  = (char*)d_ws;
  unsigned* flags = (unsigned*)base;                  //   4 KB
  int*      xT    = (int*)(base + 4096);              // 256 KB
  char*     hFA   = base + 4096 + 262144;             // 256 KB (fp16 frags)
  char*     hFB   = hFA + 262144;                     // 256 KB

  hipMemsetAsync(flags, 0, 4096, stream);

  void* args[] = { (void*)&x,
                   (void*)&Wgx, (void*)&Wgh, (void*)&Wix, (void*)&Wih,
                   (void*)&Wfx, (void*)&Wfh, (void*)&Wox, (void*)&Woh,
                   (void*)&Wph,
                   (void*)&bg, (void*)&bi, (void*)&bf, (void*)&bo, (void*)&bp,
                   (void*)&seq, (void*)&hFA, (void*)&hFB,
                   (void*)&xT, (void*)&flags };

  hipLaunchCooperativeKernel((const void*)lstm_f16, dim3(NBLK), dim3(NTHR),
                             args, 0, stream);
}